// Round 4
// baseline (509.793 us; speedup 1.0000x reference)
//
#include <hip/hip_runtime.h>

#define NPIX  (1024 * 1024)
#define NVEC  (NPIX / 4)
#define NSTAT 21
#define RBLOCKS  128   // partial blocks per batch (must equal solve block size)
#define RTHREADS 256

// ---------------------------------------------------------------------------
// Pass 1: per-batch raw sums in double precision.
// stats: 0-2 sumA_c, 3-5 sumB_c, 6-11 sym sumA_i*A_j (00,01,02,11,12,22),
//        12-20 sumB_i*A_j row-major.
// partials layout: [batch][stat][RBLOCKS] doubles (fully rewritten each call).
// ---------------------------------------------------------------------------
__global__ __launch_bounds__(RTHREADS) void reduce_stats(
    const float4* __restrict__ src, const float4* __restrict__ dst,
    double* __restrict__ partials)
{
    const int b  = blockIdx.y;
    const int pb = blockIdx.x;

    const float4* A0 = src + (size_t)b * 3 * NVEC;
    const float4* A1 = A0 + NVEC;
    const float4* A2 = A0 + 2 * NVEC;
    const float4* B0 = dst + (size_t)b * 3 * NVEC;
    const float4* B1 = B0 + NVEC;
    const float4* B2 = B0 + 2 * NVEC;

    double acc[NSTAT];
#pragma unroll
    for (int s = 0; s < NSTAT; ++s) acc[s] = 0.0;

#define ACCUM(ax0, ax1, ax2, bx0, bx1, bx2)                                  \
    do {                                                                     \
        double A0d = (ax0), A1d = (ax1), A2d = (ax2);                        \
        double B0d = (bx0), B1d = (bx1), B2d = (bx2);                        \
        acc[0] += A0d;  acc[1] += A1d;  acc[2] += A2d;                       \
        acc[3] += B0d;  acc[4] += B1d;  acc[5] += B2d;                       \
        acc[6]  += A0d * A0d; acc[7]  += A0d * A1d; acc[8]  += A0d * A2d;    \
        acc[9]  += A1d * A1d; acc[10] += A1d * A2d; acc[11] += A2d * A2d;    \
        acc[12] += B0d * A0d; acc[13] += B0d * A1d; acc[14] += B0d * A2d;    \
        acc[15] += B1d * A0d; acc[16] += B1d * A1d; acc[17] += B1d * A2d;    \
        acc[18] += B2d * A0d; acc[19] += B2d * A1d; acc[20] += B2d * A2d;    \
    } while (0)

    const int stride = RBLOCKS * RTHREADS;
    for (int p = pb * RTHREADS + threadIdx.x; p < NVEC; p += stride) {
        float4 a0 = A0[p], a1 = A1[p], a2 = A2[p];
        float4 b0 = B0[p], b1 = B1[p], b2 = B2[p];
        ACCUM(a0.x, a1.x, a2.x, b0.x, b1.x, b2.x);
        ACCUM(a0.y, a1.y, a2.y, b0.y, b1.y, b2.y);
        ACCUM(a0.z, a1.z, a2.z, b0.z, b1.z, b2.z);
        ACCUM(a0.w, a1.w, a2.w, b0.w, b1.w, b2.w);
    }
#undef ACCUM

    // wave (64-lane) butterfly reduce each stat
#pragma unroll
    for (int s = 0; s < NSTAT; ++s) {
        double v = acc[s];
        for (int off = 32; off > 0; off >>= 1) v += __shfl_down(v, off, 64);
        acc[s] = v;
    }

    __shared__ double part[RTHREADS / 64][NSTAT];
    const int lane = threadIdx.x & 63;
    const int wid  = threadIdx.x >> 6;
    if (lane == 0) {
#pragma unroll
        for (int s = 0; s < NSTAT; ++s) part[wid][s] = acc[s];
    }
    __syncthreads();

    if (threadIdx.x < NSTAT) {
        const int s = threadIdx.x;
        double v = part[0][s] + part[1][s] + part[2][s] + part[3][s];
        partials[((size_t)b * NSTAT + s) * RBLOCKS + pb] = v;
    }
}

// ---------------------------------------------------------------------------
// Pass 2: reduce partials + 3x3 solve per batch. coef[b][12] fp32:
//   0..8 = x row-major, 9..11 = offset_c = bm_c - sum_j x[c][j]*am_j
// ---------------------------------------------------------------------------
__global__ __launch_bounds__(RBLOCKS) void solve3x3(
    const double* __restrict__ partials, float* __restrict__ coef)
{
    const int b = blockIdx.x;
    const int t = threadIdx.x;  // RBLOCKS threads, 2 waves

    __shared__ double wsum[NSTAT][2];

#pragma unroll
    for (int s = 0; s < NSTAT; ++s) {
        double v = partials[((size_t)b * NSTAT + s) * RBLOCKS + t];
        for (int off = 32; off > 0; off >>= 1) v += __shfl_down(v, off, 64);
        if ((t & 63) == 0) wsum[s][t >> 6] = v;
    }
    __syncthreads();

    if (t == 0) {
        double st[NSTAT];
#pragma unroll
        for (int s = 0; s < NSTAT; ++s) st[s] = wsum[s][0] + wsum[s][1];

        const double N = (double)NPIX;
        double am[3] = {st[0] / N, st[1] / N, st[2] / N};
        double bm[3] = {st[3] / N, st[4] / N, st[5] / N};

        double AA[3][3];
        AA[0][0] = st[6]  - N * am[0] * am[0] + 0.001;
        AA[0][1] = st[7]  - N * am[0] * am[1];
        AA[0][2] = st[8]  - N * am[0] * am[2];
        AA[1][1] = st[9]  - N * am[1] * am[1] + 0.001;
        AA[1][2] = st[10] - N * am[1] * am[2];
        AA[2][2] = st[11] - N * am[2] * am[2] + 0.001;
        AA[1][0] = AA[0][1]; AA[2][0] = AA[0][2]; AA[2][1] = AA[1][2];

        double BA[3][3];
#pragma unroll
        for (int i = 0; i < 3; ++i)
#pragma unroll
            for (int j = 0; j < 3; ++j)
                BA[i][j] = st[12 + 3 * i + j] - N * bm[i] * am[j];

        // 3x3 inverse via adjugate
        double c00 =  AA[1][1] * AA[2][2] - AA[1][2] * AA[2][1];
        double c01 = -(AA[1][0] * AA[2][2] - AA[1][2] * AA[2][0]);
        double c02 =  AA[1][0] * AA[2][1] - AA[1][1] * AA[2][0];
        double det = AA[0][0] * c00 + AA[0][1] * c01 + AA[0][2] * c02;
        double id  = 1.0 / det;

        double inv[3][3];
        inv[0][0] = c00 * id;
        inv[1][0] = c01 * id;
        inv[2][0] = c02 * id;
        inv[0][1] = -(AA[0][1] * AA[2][2] - AA[0][2] * AA[2][1]) * id;
        inv[1][1] =  (AA[0][0] * AA[2][2] - AA[0][2] * AA[2][0]) * id;
        inv[2][1] = -(AA[0][0] * AA[2][1] - AA[0][1] * AA[2][0]) * id;
        inv[0][2] =  (AA[0][1] * AA[1][2] - AA[0][2] * AA[1][1]) * id;
        inv[1][2] = -(AA[0][0] * AA[1][2] - AA[0][2] * AA[1][0]) * id;
        inv[2][2] =  (AA[0][0] * AA[1][1] - AA[0][1] * AA[1][0]) * id;

        double X[3][3];
#pragma unroll
        for (int i = 0; i < 3; ++i)
#pragma unroll
            for (int j = 0; j < 3; ++j)
                X[i][j] = BA[i][0] * inv[0][j] + BA[i][1] * inv[1][j] +
                          BA[i][2] * inv[2][j];

        float* cb = coef + b * 12;
#pragma unroll
        for (int i = 0; i < 3; ++i) {
#pragma unroll
            for (int j = 0; j < 3; ++j) cb[3 * i + j] = (float)X[i][j];
            cb[9 + i] = (float)(bm[i] - (X[i][0] * am[0] + X[i][1] * am[1] +
                                         X[i][2] * am[2]));
        }
    }
}

// ---------------------------------------------------------------------------
// Pass 3: out[b][c][n] = sum_j x[c][j]*src[b][j][n] + offset[c]
// ---------------------------------------------------------------------------
__global__ __launch_bounds__(256) void apply_map(
    const float4* __restrict__ src, float4* __restrict__ out,
    const float* __restrict__ coef)
{
    const int b = blockIdx.y;
    const float* cb = coef + b * 12;
    const float x00 = cb[0], x01 = cb[1], x02 = cb[2];
    const float x10 = cb[3], x11 = cb[4], x12 = cb[5];
    const float x20 = cb[6], x21 = cb[7], x22 = cb[8];
    const float o0 = cb[9], o1 = cb[10], o2 = cb[11];

    const float4* A0 = src + (size_t)b * 3 * NVEC;
    const float4* A1 = A0 + NVEC;
    const float4* A2 = A0 + 2 * NVEC;
    float4* O0 = out + (size_t)b * 3 * NVEC;
    float4* O1 = O0 + NVEC;
    float4* O2 = O0 + 2 * NVEC;

    const int stride = gridDim.x * blockDim.x;
    for (int p = blockIdx.x * blockDim.x + threadIdx.x; p < NVEC; p += stride) {
        float4 a0 = A0[p], a1 = A1[p], a2 = A2[p];
        float4 r0, r1, r2;
#define LANE(L)                                                              \
        r0.L = fmaf(x00, a0.L, fmaf(x01, a1.L, fmaf(x02, a2.L, o0)));        \
        r1.L = fmaf(x10, a0.L, fmaf(x11, a1.L, fmaf(x12, a2.L, o1)));        \
        r2.L = fmaf(x20, a0.L, fmaf(x21, a1.L, fmaf(x22, a2.L, o2)));
        LANE(x) LANE(y) LANE(z) LANE(w)
#undef LANE
        O0[p] = r0; O1[p] = r1; O2[p] = r2;
    }
}

extern "C" void kernel_launch(void* const* d_in, const int* in_sizes, int n_in,
                              void* d_out, int out_size, void* d_ws, size_t ws_size,
                              hipStream_t stream)
{
    const float4* src = (const float4*)d_in[0];
    const float4* dst = (const float4*)d_in[1];
    float4* out = (float4*)d_out;

    const int batches = in_sizes[0] / (3 * NPIX);  // 16

    double* partials = (double*)d_ws;
    float*  coef = (float*)((char*)d_ws +
                            (size_t)batches * NSTAT * RBLOCKS * sizeof(double));

    reduce_stats<<<dim3(RBLOCKS, batches), RTHREADS, 0, stream>>>(src, dst, partials);
    solve3x3<<<batches, RBLOCKS, 0, stream>>>(partials, (float*)coef);
    apply_map<<<dim3(128, batches), 256, 0, stream>>>(src, out, coef);
}